// Round 7
// baseline (158.470 us; speedup 1.0000x reference)
//
#include <hip/hip_runtime.h>
#include <hip/hip_bf16.h>
#include <stdint.h>

typedef __bf16 bf16;
typedef __attribute__((ext_vector_type(8))) __bf16 bf16x8;
typedef __attribute__((ext_vector_type(4))) __bf16 bf16x4;
typedef __attribute__((ext_vector_type(4))) float f32x4;

#define NSEQ 1028
#define CDIM 1024
#define NHEADS 16
#define HD 64
#define BHN 64          // B*H
#define NPAD 1088       // 17*64
#define M_REAL 4112     // B*NSEQ
#define M_PAD 4224      // 33*128 (GEMM2 A-read extent)

static __device__ __forceinline__ void async_copy16(bf16* lds, const bf16* g) {
  __builtin_amdgcn_global_load_lds(
      (const __attribute__((address_space(1))) uint32_t*)g,
      (__attribute__((address_space(3))) uint32_t*)lds, 16, 0, 0);
}

// ---------------- cast fp32 -> bf16 with zero-padded tail ----------------
__global__ __launch_bounds__(256) void cast_pad_kernel(const float* __restrict__ src,
                                                       bf16* __restrict__ dst,
                                                       long n_src, long n_dst) {
  long t = (long)blockIdx.x * 256 + threadIdx.x;
  long stride = (long)gridDim.x * 256;
  for (long j = t * 4; j < n_dst; j += stride * 4) {
    bf16x4 o;
    if (j + 4 <= n_src) {
      float4 v = *(const float4*)(src + j);
      o[0] = (bf16)v.x; o[1] = (bf16)v.y; o[2] = (bf16)v.z; o[3] = (bf16)v.w;
    } else {
      for (int k = 0; k < 4; k++) o[k] = (bf16)((j + k < n_src) ? src[j + k] : 0.0f);
    }
    *(bf16x4*)(dst + j) = o;
  }
}

// ============ GEMM1: 256x256 tile, BK=64, 8-phase, DE-PINNED ==============
// C[m][n] = sum_k A[m][k] * W[n][k], K=1024, N=3072. 512 thr = 8 waves.
// vs R6: no sched_barrier(0), no per-phase lgkm drain before MFMA (C++ loads
// -> compiler emits incremental lgkmcnt; m141 showed pinning costs ~40%).
// lgkmcnt(0) kept ONLY at ph2-end (Bs[cur] reuse by ph3 stage) and ph4-end
// (As[cur] reuse by next tile's stage) - free by then. Counted vmcnt(4),
// raw barriers, setprio, T2 source-swizzle, T1 bijective XCD swizzle kept.
// 17 m-tiles: last starts at M_REAL-256 (overlap rows double-write same data).
__global__ __launch_bounds__(512, 2) void gemm_qkv_256(
    const bf16* __restrict__ A, const bf16* __restrict__ Bm,
    bf16* __restrict__ q_bf, bf16* __restrict__ k_bf, bf16* __restrict__ v_raw,
    const float* __restrict__ cosb, const float* __restrict__ sinb,
    const float* __restrict__ nqw, const float* __restrict__ nkw) {
  constexpr int K = CDIM;       // 1024
  constexpr int NT = K / 64;    // 16 K-tiles
  __shared__ __attribute__((aligned(16))) bf16 As[2 * 2 * 128 * 64];
  __shared__ __attribute__((aligned(16))) bf16 Bs[2 * 2 * 128 * 64];
  const int tid = threadIdx.x;
  const int lane = tid & 63;
  const int wid = tid >> 6;
  const int wr = wid >> 2;      // 0..1: rows [wr*128, +128)
  const int wc = wid & 3;       // 0..3: cols [wc*64, +64)
  const int l15 = lane & 15, l4 = lane >> 4;
  const int rsw = l15 & 7;      // T2 chunk XOR

  const int nwg = gridDim.x;    // 204
  const int qq = nwg >> 3, rr = nwg & 7;
  const int xcd = blockIdx.x & 7, pos = blockIdx.x >> 3;
  const int work = (xcd < rr ? xcd * (qq + 1) : rr * (qq + 1) + (xcd - rr) * qq) + pos;
  const int n0 = (work % 12) << 8;
  const int mi = work / 12;
  const int m0 = (mi < 16) ? (mi << 8) : (M_REAL - 256);

  f32x4 acc[8][4] = {};
  bf16x8 afr[4][2], bfr0[2][2], bfr1[2][2];

  size_t a_src[2], b_src[2];
#pragma unroll
  for (int s = 0; s < 2; s++) {
    int idx = tid + s * 512;
    int row = idx >> 3, ch = idx & 7, chs = ch ^ (row & 7);
    a_src[s] = (size_t)(m0 + row) * K + (chs << 3);
    b_src[s] = (size_t)(n0 + row) * K + (chs << 3);
  }

#define STAGE_A(bufi, h, tt)                                                   \
  { _Pragma("unroll") for (int s = 0; s < 2; s++)                              \
      async_copy16(&As[((bufi) * 2 + (h)) * 8192 + (tid + s * 512) * 8],       \
                   A + a_src[s] + (size_t)(h) * (128 * K) + (size_t)(tt) * 64); }
#define STAGE_B(bufi, h, tt)                                                   \
  { _Pragma("unroll") for (int s = 0; s < 2; s++)                              \
      async_copy16(&Bs[((bufi) * 2 + (h)) * 8192 + (tid + s * 512) * 8],       \
                   Bm + b_src[s] + (size_t)(h) * (128 * K) + (size_t)(tt) * 64); }
#define LDA_FRAG(mq)                                                           \
  { _Pragma("unroll") for (int ii = 0; ii < 4; ii++)                           \
      _Pragma("unroll") for (int kk = 0; kk < 2; kk++)                         \
        afr[ii][kk] = *(const bf16x8*)&As[abase + (((mq)*4 + ii) * 16 + l15) * 64 + \
                                          (((kk * 4 + l4) ^ rsw) << 3)]; }
#define LDB_FRAG(dst, nq)                                                      \
  { _Pragma("unroll") for (int jj = 0; jj < 2; jj++)                           \
      _Pragma("unroll") for (int kk = 0; kk < 2; kk++)                         \
        dst[jj][kk] = *(const bf16x8*)&Bs[bbase + ((wc & 1) * 64 + ((nq)*2 + jj) * 16 + l15) * 64 + \
                                          (((kk * 4 + l4) ^ rsw) << 3)]; }
#define MFMA_Q(mq, nq, bb)                                                     \
  { _Pragma("unroll") for (int ii = 0; ii < 4; ii++)                           \
      _Pragma("unroll") for (int jj = 0; jj < 2; jj++)                         \
        _Pragma("unroll") for (int kk = 0; kk < 2; kk++)                       \
          acc[(mq)*4 + ii][(nq)*2 + jj] = __builtin_amdgcn_mfma_f32_16x16x32_bf16( \
              afr[ii][kk], bb[jj][kk], acc[(mq)*4 + ii][(nq)*2 + jj], 0, 0, 0); }

  // prologue: t0{A0,A1,B0,B1}, t1{B0,B1}; vmcnt(4) -> t0 landed
  STAGE_A(0, 0, 0); STAGE_A(0, 1, 0); STAGE_B(0, 0, 0); STAGE_B(0, 1, 0);
  STAGE_B(1, 0, 1); STAGE_B(1, 1, 1);
  asm volatile("s_waitcnt vmcnt(4)" ::: "memory");
  __builtin_amdgcn_s_barrier();

  for (int t = 0; t < NT; ++t) {
    const int cur = t & 1, nxt = cur ^ 1;
    const int abase = (cur * 2 + wr) * 8192;
    const int bbase = (cur * 2 + (wc >> 1)) * 8192;
    // ---- phase 1 ----
    LDA_FRAG(0); LDB_FRAG(bfr0, 0);
    if (t + 1 < NT) STAGE_A(nxt, 0, t + 1);
    __builtin_amdgcn_s_barrier();
    __builtin_amdgcn_s_setprio(1);
    MFMA_Q(0, 0, bfr0);
    __builtin_amdgcn_s_setprio(0);
    __builtin_amdgcn_s_barrier();
    // ---- phase 2 ----
    LDB_FRAG(bfr1, 1);
    if (t + 1 < NT) STAGE_A(nxt, 1, t + 1);
    __builtin_amdgcn_s_barrier();
    __builtin_amdgcn_s_setprio(1);
    MFMA_Q(0, 1, bfr1);
    __builtin_amdgcn_s_setprio(0);
    asm volatile("s_waitcnt lgkmcnt(0)" ::: "memory");  // Bs[cur] reads done
    __builtin_amdgcn_s_barrier();
    // ---- phase 3 ----
    LDA_FRAG(1);
    if (t + 2 < NT) STAGE_B(cur, 0, t + 2);
    __builtin_amdgcn_s_barrier();
    __builtin_amdgcn_s_setprio(1);
    MFMA_Q(1, 0, bfr0);
    __builtin_amdgcn_s_setprio(0);
    __builtin_amdgcn_s_barrier();
    // ---- phase 4 ----
    if (t + 2 < NT) {
      STAGE_B(cur, 1, t + 2);
      asm volatile("s_waitcnt vmcnt(4)" ::: "memory");
    } else {
      asm volatile("s_waitcnt vmcnt(0)" ::: "memory");
    }
    __builtin_amdgcn_s_barrier();
    __builtin_amdgcn_s_setprio(1);
    MFMA_Q(1, 1, bfr1);
    __builtin_amdgcn_s_setprio(0);
    asm volatile("s_waitcnt lgkmcnt(0)" ::: "memory");  // As[cur] reads done
    __builtin_amdgcn_s_barrier();
  }
#undef STAGE_A
#undef STAGE_B
#undef LDA_FRAG
#undef LDB_FRAG
#undef MFMA_Q

  // epilogue: C/D layout col = lane&15, row = (lane>>4)*4 + reg
  const int d_base = n0 + wc * 64;
  const int tsel = d_base >> 10;
  const int hh = (d_base & 1023) >> 6;
  if (tsel == 2) {
#pragma unroll
    for (int i = 0; i < 8; i++)
#pragma unroll
      for (int r = 0; r < 4; r++) {
        int m = m0 + wr * 128 + i * 16 + l4 * 4 + r;
        if (m < M_REAL) {
          int b = m / NSEQ, n = m % NSEQ;
          size_t rb = ((size_t)(b * NHEADS + hh) * NSEQ + n) * HD;
#pragma unroll
          for (int j = 0; j < 4; j++)
            v_raw[rb + j * 16 + l15] = (bf16)acc[i][j][r];
        }
      }
  } else {
    const float* wn = (tsel == 0) ? nqw : nkw;
    bf16* dst = (tsel == 0) ? q_bf : k_bf;
    float wv[4];
#pragma unroll
    for (int j = 0; j < 4; j++) wv[j] = wn[j * 16 + l15];
#pragma unroll
    for (int i = 0; i < 8; i++)
#pragma unroll
      for (int r = 0; r < 4; r++) {
        int m = m0 + wr * 128 + i * 16 + l4 * 4 + r;
        if (m >= M_REAL) continue;
        float ss = 0.0f;
#pragma unroll
        for (int j = 0; j < 4; j++) { float x = acc[i][j][r]; ss += x * x; }
        ss += __shfl_xor(ss, 1);
        ss += __shfl_xor(ss, 2);
        ss += __shfl_xor(ss, 4);
        ss += __shfl_xor(ss, 8);
        float rms = rsqrtf(ss * (1.0f / HD) + 1e-6f);
        int b = m / NSEQ, n = m % NSEQ;
        float qn[4];
#pragma unroll
        for (int j = 0; j < 4; j++) qn[j] = acc[i][j][r] * rms * wv[j];
        size_t rb = ((size_t)(b * NHEADS + hh) * NPAD + n) * HD;
#pragma unroll
        for (int j = 0; j < 4; j++) {
          float c = cosb[n * HD + j * 16 + l15];
          float s = sinb[n * HD + j * 16 + l15];
          float rot = (j < 2) ? -qn[j + 2] : qn[j - 2];
          dst[rb + j * 16 + l15] = (bf16)(qn[j] * c + rot * s);
        }
      }
  }
}

// ---- GEMM2: 128x128 tile, split-K x2 (K=512 each), atomicAdd epilogue ----
// 528 blocks (~2.06/CU): halves the per-block serial K-chain and doubles
// block-level overlap. out must be zeroed before launch (memset on stream).
__global__ __launch_bounds__(256) void gemm_out_kernel(
    const bf16* __restrict__ A, const bf16* __restrict__ Bm,
    float* __restrict__ outF) {
  constexpr int LDK = CDIM;    // row stride 1024
  constexpr int KH = 512;      // K half
  constexpr int N = CDIM;      // 1024
  __shared__ __attribute__((aligned(16))) bf16 As[2][128 * 64];
  __shared__ __attribute__((aligned(16))) bf16 Bs[2][128 * 64];
  const int tid = threadIdx.x;
  const int lane = tid & 63;
  const int wid = tid >> 6;
  const int wr = wid >> 1, wc = wid & 1;
  const int l15 = lane & 15, l4 = lane >> 4;

  const int nwg = gridDim.x;   // 528 (%8==0)
  const int cpx = nwg >> 3;
  const int work = (blockIdx.x & 7) * cpx + (blockIdx.x >> 3);
  const int ks = work / 264;   // K-half index
  const int rem = work % 264;
  const int n0 = (rem & 7) << 7;
  const int m0 = (rem >> 3) << 7;
  const size_t kbase = (size_t)ks * KH;

  f32x4 acc[4][4] = {};

  size_t a_base[4], b_base[4];
#pragma unroll
  for (int s = 0; s < 4; s++) {
    int c = tid + s * 256;
    int row = c >> 3, ch = c & 7;
    int chs = ch ^ (row & 7);
    a_base[s] = (size_t)(m0 + row) * LDK + kbase + (chs << 3);
    b_base[s] = (size_t)(n0 + row) * LDK + kbase + (chs << 3);
  }

#define STAGE(bufi, ktof)                                         \
  {                                                               \
    _Pragma("unroll")                                             \
    for (int s = 0; s < 4; s++) {                                 \
      int c = tid + s * 256;                                      \
      async_copy16(&As[bufi][c * 8], A + a_base[s] + (ktof));     \
      async_copy16(&Bs[bufi][c * 8], Bm + b_base[s] + (ktof));    \
    }                                                             \
  }

  const int nt = KH >> 6;  // 8
  STAGE(0, 0);

  for (int t = 0; t < nt; ++t) {
    if (t + 1 < nt) {
      STAGE((t + 1) & 1, (t + 1) << 6);
      asm volatile("s_waitcnt vmcnt(8)" ::: "memory");
    } else {
      asm volatile("s_waitcnt vmcnt(0)" ::: "memory");
    }
    __builtin_amdgcn_s_barrier();

    const int rsw = l15 & 7;
    const int cur = t & 1;
    bf16x8 af[2][4], bfr[2][4];
#pragma unroll
    for (int h = 0; h < 2; h++)
#pragma unroll
      for (int i = 0; i < 4; i++)
        af[h][i] = *(const bf16x8*)&As[cur][(wr * 64 + i * 16 + l15) * 64 +
                                            (((h * 4 + l4) ^ rsw) << 3)];
#pragma unroll
    for (int h = 0; h < 2; h++)
#pragma unroll
      for (int j = 0; j < 4; j++)
        bfr[h][j] = *(const bf16x8*)&Bs[cur][(wc * 64 + j * 16 + l15) * 64 +
                                             (((h * 4 + l4) ^ rsw) << 3)];

#pragma unroll
    for (int h = 0; h < 2; h++)
#pragma unroll
      for (int i = 0; i < 4; i++)
#pragma unroll
        for (int j = 0; j < 4; j++)
          acc[i][j] = __builtin_amdgcn_mfma_f32_16x16x32_bf16(af[h][i], bfr[h][j], acc[i][j], 0, 0, 0);

    asm volatile("s_waitcnt lgkmcnt(0)" ::: "memory");
    __builtin_amdgcn_s_barrier();
  }
#undef STAGE

#pragma unroll
  for (int i = 0; i < 4; i++)
#pragma unroll
    for (int j = 0; j < 4; j++) {
      int d = n0 + wc * 64 + j * 16 + l15;
      int mrow = m0 + wr * 64 + i * 16 + l4 * 4;
#pragma unroll
      for (int r = 0; r < 4; r++) {
        int m = mrow + r;
        if (m < M_REAL) atomicAdd(&outF[(size_t)m * N + d], acc[i][j][r]);
      }
    }
}

// ---- V transpose: v_raw [bh][n][64] -> vT [bh][64][NPAD] patch-aligned ----
__global__ __launch_bounds__(256) void v_transpose_kernel(const bf16* __restrict__ v_raw,
                                                          bf16* __restrict__ vT) {
  __shared__ bf16 tile[64][65];
  int bh = blockIdx.y, c = blockIdx.x;
  int tid = threadIdx.x;
#pragma unroll
  for (int jj = 0; jj < 16; jj++) {
    int idx = tid + jj * 256;
    int i = idx >> 6, e = idx & 63;
    int n = (c == 0) ? i : (64 * c - 60 + i);
    bool ok = (c == 0) ? (i < 4) : (n < NSEQ);
    tile[i][e] = ok ? v_raw[((size_t)bh * NSEQ + n) * HD + e] : (bf16)0.0f;
  }
  __syncthreads();
#pragma unroll
  for (int jj = 0; jj < 16; jj++) {
    int idx = tid + jj * 256;
    int e = idx >> 6, i = idx & 63;
    vT[((size_t)bh * HD + e) * NPAD + 64 * c + i] = tile[i][e];
  }
}

// ---------------- masked flash attention (balanced tiling) ---------------
__global__ __launch_bounds__(256) void attn_kernel(
    const bf16* __restrict__ Q, const bf16* __restrict__ Kb, const bf16* __restrict__ Vt,
    bf16* __restrict__ att, const int* __restrict__ winp) {
  __shared__ __attribute__((aligned(16))) bf16 P_s[4][16][72];
  __shared__ float o_s[4][4][64];
  __shared__ float ml_s[4][2][16];
  const int bh = blockIdx.y, qt = blockIdx.x;
  const int W = winp[0];
  const int tid = threadIdx.x, w = tid >> 6, lane = tid & 63;
  const int l15 = lane & 15, l4 = lane >> 4;
  const size_t qkbase = (size_t)bh * NPAD * HD;
  const size_t vtb = (size_t)bh * HD * NPAD;
  const bool is_spec = (qt == 16);

  const int qrow0 = is_spec ? 0 : (4 + qt * 64 + w * 16);
  bf16x8 aq0 = *(const bf16x8*)&Q[qkbase + (size_t)(qrow0 + l15) * HD + l4 * 8];
  bf16x8 aq1 = *(const bf16x8*)&Q[qkbase + (size_t)(qrow0 + l15) * HD + 32 + l4 * 8];

  float mrow[4], lrow[4];
  f32x4 o[4] = {};
#pragma unroll
  for (int r = 0; r < 4; r++) { mrow[r] = -1e30f; lrow[r] = 0.0f; }

  int p0, pstep, pmax, toff;
  if (is_spec) {
    p0 = w; pstep = 4; pmax = 16; toff = -1;
  } else {
    int ta = ((2 * qt - W + 64) >> 1) - 32;
    int tb = (2 * qt + 1 + W) >> 1;
    ta = ta < 0 ? 0 : ta;
    tb = tb > 15 ? 15 : tb;
    p0 = 0; pstep = 1; pmax = tb - ta + 1; toff = ta - 1;
  }

  for (int p = p0; p <= pmax; p += pstep) {
    const bool sp = (p == 0);
    const int tau = toff + p;
    const int krow0 = sp ? 0 : (4 + tau * 64);
    const int vcol0 = sp ? 0 : (64 + tau * 64);

    f32x4 sacc[4] = {};
#pragma unroll
    for (int kf = 0; kf < 4; kf++) {
      const bf16* kp = &Kb[qkbase + (size_t)(krow0 + kf * 16 + l15) * HD];
      bf16x8 b0 = *(const bf16x8*)(kp + l4 * 8);
      bf16x8 b1 = *(const bf16x8*)(kp + 32 + l4 * 8);
      sacc[kf] = __builtin_amdgcn_mfma_f32_16x16x32_bf16(aq0, b0, sacc[kf], 0, 0, 0);
      sacc[kf] = __builtin_amdgcn_mfma_f32_16x16x32_bf16(aq1, b1, sacc[kf], 0, 0, 0);
    }

    float pvv[4][4];
#pragma unroll
    for (int kf = 0; kf < 4; kf++)
#pragma unroll
      for (int r = 0; r < 4; r++) {
        float s = sacc[kf][r] * 0.125f;
        bool valid;
        if (sp) {
          valid = (kf == 0) && (l15 < 4);
        } else if (is_spec) {
          valid = true;
        } else {
          int p_k = tau * 64 + kf * 16 + l15;
          int p_q = qt * 64 + w * 16 + l4 * 4 + r;
          int dr = (p_q >> 5) - (p_k >> 5); dr = dr < 0 ? -dr : dr;
          int dc = (p_q & 31) - (p_k & 31); dc = dc < 0 ? -dc : dc;
          valid = (dr <= W) && (dc <= W);
        }
        pvv[kf][r] = valid ? s : -1e30f;
      }

#pragma unroll
    for (int r = 0; r < 4; r++) {
      float mx = fmaxf(fmaxf(pvv[0][r], pvv[1][r]), fmaxf(pvv[2][r], pvv[3][r]));
#pragma unroll
      for (int mm = 1; mm < 16; mm <<= 1) mx = fmaxf(mx, __shfl_xor(mx, mm));
      float mnew = fmaxf(mrow[r], mx);
      float scale = __expf(mrow[r] - mnew);
      float rs = 0.0f;
#pragma unroll
      for (int kf = 0; kf < 4; kf++) {
        float pp = __expf(pvv[kf][r] - mnew);
        pvv[kf][r] = pp;
        rs += pp;
      }
#pragma unroll
      for (int mm = 1; mm < 16; mm <<= 1) rs += __shfl_xor(rs, mm);
      lrow[r] = lrow[r] * scale + rs;
      mrow[r] = mnew;
#pragma unroll
      for (int f = 0; f < 4; f++) o[f][r] *= scale;
    }

#pragma unroll
    for (int kf = 0; kf < 4; kf++)
#pragma unroll
      for (int r = 0; r < 4; r++)
        P_s[w][l4 * 4 + r][kf * 16 + l15] = (bf16)pvv[kf][r];

    bf16x8 pa0 = *(const bf16x8*)&P_s[w][l15][l4 * 8];
    bf16x8 pa1 = *(const bf16x8*)&P_s[w][l15][32 + l4 * 8];
#pragma unroll
    for (int f = 0; f < 4; f++) {
      const bf16* vp = &Vt[vtb + (size_t)(f * 16 + l15) * NPAD + vcol0];
      bf16x8 v0 = *(const bf16x8*)(vp + l4 * 8);
      bf16x8 v1 = *(const bf16x8*)(vp + 32 + l4 * 8);
      o[f] = __builtin_amdgcn_mfma_f32_16x16x32_bf16(pa0, v0, o[f], 0, 0, 0);
      o[f] = __builtin_amdgcn_mfma_f32_16x16x32_bf16(pa1, v1, o[f], 0, 0, 0);
    }
  }

  const int b = bh >> 4, h = bh & 15;
  if (!is_spec) {
#pragma unroll
    for (int f = 0; f < 4; f++)
#pragma unroll
      for (int r = 0; r < 4; r++) {
        int n = qrow0 + l4 * 4 + r;
        att[((size_t)(b * NSEQ + n)) * CDIM + h * HD + f * 16 + l15] =
            (bf16)(o[f][r] / lrow[r]);
      }
  } else {
    if (l4 == 0) {
#pragma unroll
      for (int f = 0; f < 4; f++)
#pragma unroll
        for (int r = 0; r < 4; r++) o_s[w][r][f * 16 + l15] = o[f][r];
      if (l15 == 0)
#pragma unroll
        for (int r = 0; r < 4; r++) { ml_s[w][0][r] = mrow[r]; ml_s[w][1][r] = lrow[r]; }
    }
    __syncthreads();
    int row = tid >> 6, dim = tid & 63;
    float M = -1e30f;
#pragma unroll
    for (int ww = 0; ww < 4; ww++) M = fmaxf(M, ml_s[ww][0][row]);
    float L = 0.0f, val = 0.0f;
#pragma unroll
    for (int ww = 0; ww < 4; ww++) {
      float e = __expf(ml_s[ww][0][row] - M);
      L += e * ml_s[ww][1][row];
      val += e * o_s[ww][row][dim];
    }
    att[((size_t)(b * NSEQ + row)) * CDIM + h * HD + dim] = (bf16)(val / L);
  }
}

// ------------------------------------------------------------------------
extern "C" void kernel_launch(void* const* d_in, const int* in_sizes, int n_in,
                              void* d_out, int out_size, void* d_ws, size_t ws_size,
                              hipStream_t stream) {
  const float* hidden = (const float*)d_in[0];
  const float* cosb = (const float*)d_in[1];
  const float* sinb = (const float*)d_in[2];
  const float* qkv_w = (const float*)d_in[3];
  const float* out_w = (const float*)d_in[4];
  const float* norm_q_w = (const float*)d_in[5];
  const float* norm_k_w = (const float*)d_in[6];
  const int* win = (const int*)d_in[7];
  float* out = (float*)d_out;

  char* ws = (char*)d_ws;
  size_t off = 0;
  auto alloc = [&](size_t bytes) {
    char* p = ws + off;
    off += (bytes + 255) & ~(size_t)255;
    return p;
  };
  bf16* A_bf  = (bf16*)alloc((size_t)M_REAL * CDIM * 2);
  bf16* W1    = (bf16*)alloc((size_t)3 * CDIM * CDIM * 2);
  bf16* W2    = (bf16*)alloc((size_t)CDIM * CDIM * 2);
  bf16* v_raw = (bf16*)alloc((size_t)BHN * NSEQ * HD * 2);
  bf16* q_bf  = (bf16*)alloc((size_t)BHN * NPAD * HD * 2);
  bf16* k_bf  = (bf16*)alloc((size_t)BHN * NPAD * HD * 2);
  bf16* vT    = (bf16*)alloc((size_t)BHN * HD * NPAD * 2);
  bf16* att   = (bf16*)alloc((size_t)M_PAD * CDIM * 2);
  (void)ws_size; (void)in_sizes; (void)n_in; (void)out_size;

  // zero d_out for split-K atomic accumulation (graph-capture legal)
  hipMemsetAsync(out, 0, (size_t)M_REAL * CDIM * sizeof(float), stream);

  cast_pad_kernel<<<2048, 256, 0, stream>>>(hidden, A_bf, (long)M_REAL * CDIM, (long)M_REAL * CDIM);
  cast_pad_kernel<<<1024, 256, 0, stream>>>(qkv_w, W1, (long)3 * CDIM * CDIM, (long)3 * CDIM * CDIM);
  cast_pad_kernel<<<512, 256, 0, stream>>>(out_w, W2, (long)CDIM * CDIM, (long)CDIM * CDIM);

  // GEMM1: 17 m-tiles x 12 n-tiles = 204 blocks, 512 threads, 8-phase de-pinned
  gemm_qkv_256<<<204, 512, 0, stream>>>(A_bf, W1, q_bf, k_bf, v_raw,
                                        cosb, sinb, norm_q_w, norm_k_w);
  v_transpose_kernel<<<dim3(17, 64), 256, 0, stream>>>(v_raw, vT);
  attn_kernel<<<dim3(17, 64), 256, 0, stream>>>(q_bf, k_bf, vT, att, win);
  // GEMM2: 33 m-tiles x 8 n-tiles x 2 K-halves = 528 blocks, atomic epilogue
  gemm_out_kernel<<<528, 256, 0, stream>>>(att, W2, out);
}

// Round 8
// 136.783 us; speedup vs baseline: 1.1586x; 1.1586x over previous
//
#include <hip/hip_runtime.h>
#include <hip/hip_bf16.h>
#include <stdint.h>

typedef __bf16 bf16;
typedef __attribute__((ext_vector_type(8))) __bf16 bf16x8;
typedef __attribute__((ext_vector_type(4))) __bf16 bf16x4;
typedef __attribute__((ext_vector_type(4))) float f32x4;

#define NSEQ 1028
#define CDIM 1024
#define NHEADS 16
#define HD 64
#define BHN 64          // B*H
#define NPAD 1088       // 17*64
#define M_REAL 4112     // B*NSEQ
#define MTILES 33       // 33 m-tiles of 128 (last overlaps: starts at M_REAL-128)

static __device__ __forceinline__ void async_copy16(bf16* lds, const bf16* g) {
  __builtin_amdgcn_global_load_lds(
      (const __attribute__((address_space(1))) uint32_t*)g,
      (__attribute__((address_space(3))) uint32_t*)lds, 16, 0, 0);
}

// ---------------- cast fp32 -> bf16 ----------------
__global__ __launch_bounds__(256) void cast_pad_kernel(const float* __restrict__ src,
                                                       bf16* __restrict__ dst,
                                                       long n_src, long n_dst) {
  long t = (long)blockIdx.x * 256 + threadIdx.x;
  long stride = (long)gridDim.x * 256;
  for (long j = t * 4; j < n_dst; j += stride * 4) {
    bf16x4 o;
    if (j + 4 <= n_src) {
      float4 v = *(const float4*)(src + j);
      o[0] = (bf16)v.x; o[1] = (bf16)v.y; o[2] = (bf16)v.z; o[3] = (bf16)v.w;
    } else {
      for (int k = 0; k < 4; k++) o[k] = (bf16)((j + k < n_src) ? src[j + k] : 0.0f);
    }
    *(bf16x4*)(dst + j) = o;
  }
}

// ---- bf16 MFMA GEMM, 128x128 tile, BK=64, dbuf + counted vmcnt (T4) ------
// C[m][n] = sum_k A[m][k] * Bm[n][k], K = CDIM = 1024.
// XCD WEIGHT-PINNING mapping (R8): blockIdx = xcd(0..7) + 8*pos;
//   pos = nloc + NSTRIP*mi  ->  n0 = (xcd*NSTRIP + nloc)*128, m0 = mi*128.
// Each XCD's B working set = NSTRIP*128 cols * 1024 K * 2B (0.75MB / 0.25MB)
// stays L2-resident for the whole kernel; A streams from L3. Removes the
// per-K-step B-stage L3/HBM latency all prior schedule variants shared.
// Last m-tile starts at M_REAL-128 (overlap rows double-write same values).
// T2 source-chunk XOR swizzle (0 bank conflicts, verified R4).
// EPI==0: fused RMS-norm+rope epilogue -> q_bf/k_bf [bh][NPAD][64] + v_raw.
// EPI==1: fp32 C row-major (N = NSTRIP*8*128 columns).
template <int EPI, int NSTRIP>
__global__ __launch_bounds__(256) void gemm_bf16_kernel(
    const bf16* __restrict__ A, const bf16* __restrict__ Bm,
    bf16* __restrict__ q_bf, bf16* __restrict__ k_bf, bf16* __restrict__ v_raw,
    float* __restrict__ outF,
    const float* __restrict__ cosb, const float* __restrict__ sinb,
    const float* __restrict__ nqw, const float* __restrict__ nkw) {
  constexpr int K = CDIM;
  constexpr int N = NSTRIP * 8 * 128;
  __shared__ __attribute__((aligned(16))) bf16 As[2][128 * 64];
  __shared__ __attribute__((aligned(16))) bf16 Bs[2][128 * 64];
  const int tid = threadIdx.x;
  const int lane = tid & 63;
  const int wid = tid >> 6;
  const int wr = wid >> 1, wc = wid & 1;
  const int l15 = lane & 15, l4 = lane >> 4;

  // XCD weight-pinning work mapping
  const int xcd = blockIdx.x & 7;
  const int pos = blockIdx.x >> 3;          // 0 .. NSTRIP*MTILES-1
  const int nloc = pos % NSTRIP;
  const int mi = pos / NSTRIP;
  const int n0 = (xcd * NSTRIP + nloc) << 7;
  const int m0 = (mi < MTILES - 1) ? (mi << 7) : (M_REAL - 128);

  f32x4 acc[4][4] = {};

  // staging source addresses with XOR-swizzled 16B-chunk index (T2)
  size_t a_base[4], b_base[4];
#pragma unroll
  for (int s = 0; s < 4; s++) {
    int c = tid + s * 256;
    int row = c >> 3, ch = c & 7;
    int chs = ch ^ (row & 7);
    a_base[s] = (size_t)(m0 + row) * K + (chs << 3);
    b_base[s] = (size_t)(n0 + row) * K + (chs << 3);
  }

#define STAGE(bufi, ktof)                                         \
  {                                                               \
    _Pragma("unroll")                                             \
    for (int s = 0; s < 4; s++) {                                 \
      int c = tid + s * 256;                                      \
      async_copy16(&As[bufi][c * 8], A + a_base[s] + (ktof));     \
      async_copy16(&Bs[bufi][c * 8], Bm + b_base[s] + (ktof));    \
    }                                                             \
  }

  const int nt = K >> 6;
  STAGE(0, 0);  // 8 loads/thread in flight

  for (int t = 0; t < nt; ++t) {
    if (t + 1 < nt) {
      STAGE((t + 1) & 1, (t + 1) << 6);
      asm volatile("s_waitcnt vmcnt(8)" ::: "memory");   // tile t landed
    } else {
      asm volatile("s_waitcnt vmcnt(0)" ::: "memory");
    }
    __builtin_amdgcn_s_barrier();  // raw barrier: tile t+1 stays in flight

    const int rsw = l15 & 7;
    const int cur = t & 1;
    bf16x8 af[2][4], bfr[2][4];
#pragma unroll
    for (int h = 0; h < 2; h++)
#pragma unroll
      for (int i = 0; i < 4; i++)
        af[h][i] = *(const bf16x8*)&As[cur][(wr * 64 + i * 16 + l15) * 64 +
                                            (((h * 4 + l4) ^ rsw) << 3)];
#pragma unroll
    for (int h = 0; h < 2; h++)
#pragma unroll
      for (int j = 0; j < 4; j++)
        bfr[h][j] = *(const bf16x8*)&Bs[cur][(wc * 64 + j * 16 + l15) * 64 +
                                             (((h * 4 + l4) ^ rsw) << 3)];

#pragma unroll
    for (int h = 0; h < 2; h++)
#pragma unroll
      for (int i = 0; i < 4; i++)
#pragma unroll
        for (int j = 0; j < 4; j++)
          acc[i][j] = __builtin_amdgcn_mfma_f32_16x16x32_bf16(af[h][i], bfr[h][j], acc[i][j], 0, 0, 0);

    asm volatile("s_waitcnt lgkmcnt(0)" ::: "memory");   // buf[cur] reads done
    __builtin_amdgcn_s_barrier();
  }
#undef STAGE

  // epilogue: C/D layout col = lane&15, row = (lane>>4)*4 + reg
  if (EPI == 0) {
    const int d_base = n0 + wc * 64;      // 64-aligned -> one (matrix, head)
    const int tsel = d_base >> 10;
    const int hh = (d_base & 1023) >> 6;
    if (tsel == 2) {
#pragma unroll
      for (int i = 0; i < 4; i++)
#pragma unroll
        for (int r = 0; r < 4; r++) {
          int m = m0 + wr * 64 + i * 16 + l4 * 4 + r;   // always < M_REAL
          int b = m / NSEQ, n = m % NSEQ;
          size_t rb = ((size_t)(b * NHEADS + hh) * NSEQ + n) * HD;
#pragma unroll
          for (int j = 0; j < 4; j++)
            v_raw[rb + j * 16 + l15] = (bf16)acc[i][j][r];
        }
    } else {
      const float* wn = (tsel == 0) ? nqw : nkw;
      bf16* dst = (tsel == 0) ? q_bf : k_bf;
      float wv[4];
#pragma unroll
      for (int j = 0; j < 4; j++) wv[j] = wn[j * 16 + l15];
#pragma unroll
      for (int i = 0; i < 4; i++)
#pragma unroll
        for (int r = 0; r < 4; r++) {
          int m = m0 + wr * 64 + i * 16 + l4 * 4 + r;   // uniform across l15 group
          float ss = 0.0f;
#pragma unroll
          for (int j = 0; j < 4; j++) { float x = acc[i][j][r]; ss += x * x; }
          ss += __shfl_xor(ss, 1);
          ss += __shfl_xor(ss, 2);
          ss += __shfl_xor(ss, 4);
          ss += __shfl_xor(ss, 8);
          float rms = rsqrtf(ss * (1.0f / HD) + 1e-6f);
          int b = m / NSEQ, n = m % NSEQ;
          float qn[4];
#pragma unroll
          for (int j = 0; j < 4; j++) qn[j] = acc[i][j][r] * rms * wv[j];
          size_t rb = ((size_t)(b * NHEADS + hh) * NPAD + n) * HD;
#pragma unroll
          for (int j = 0; j < 4; j++) {
            float c = cosb[n * HD + j * 16 + l15];
            float s = sinb[n * HD + j * 16 + l15];
            float rot = (j < 2) ? -qn[j + 2] : qn[j - 2];
            dst[rb + j * 16 + l15] = (bf16)(qn[j] * c + rot * s);
          }
        }
    }
  } else {
#pragma unroll
    for (int i = 0; i < 4; i++)
#pragma unroll
      for (int j = 0; j < 4; j++) {
        int d = n0 + wc * 64 + j * 16 + l15;
        int mrow = m0 + wr * 64 + i * 16 + l4 * 4;
#pragma unroll
        for (int r = 0; r < 4; r++) {
          int m = mrow + r;   // always < M_REAL (overlap tile double-writes)
          outF[(size_t)m * N + d] = acc[i][j][r];
        }
      }
  }
}

// ---- V transpose: v_raw [bh][n][64] -> vT [bh][64][NPAD] patch-aligned ----
__global__ __launch_bounds__(256) void v_transpose_kernel(const bf16* __restrict__ v_raw,
                                                          bf16* __restrict__ vT) {
  __shared__ bf16 tile[64][65];
  int bh = blockIdx.y, c = blockIdx.x;
  int tid = threadIdx.x;
#pragma unroll
  for (int jj = 0; jj < 16; jj++) {
    int idx = tid + jj * 256;
    int i = idx >> 6, e = idx & 63;
    int n = (c == 0) ? i : (64 * c - 60 + i);
    bool ok = (c == 0) ? (i < 4) : (n < NSEQ);
    tile[i][e] = ok ? v_raw[((size_t)bh * NSEQ + n) * HD + e] : (bf16)0.0f;
  }
  __syncthreads();
#pragma unroll
  for (int jj = 0; jj < 16; jj++) {
    int idx = tid + jj * 256;
    int e = idx >> 6, i = idx & 63;
    vT[((size_t)bh * HD + e) * NPAD + 64 * c + i] = tile[i][e];
  }
}

// ---------------- masked flash attention (balanced tiling) ---------------
__global__ __launch_bounds__(256) void attn_kernel(
    const bf16* __restrict__ Q, const bf16* __restrict__ Kb, const bf16* __restrict__ Vt,
    bf16* __restrict__ att, const int* __restrict__ winp) {
  __shared__ __attribute__((aligned(16))) bf16 P_s[4][16][72];
  __shared__ float o_s[4][4][64];
  __shared__ float ml_s[4][2][16];
  const int bh = blockIdx.y, qt = blockIdx.x;
  const int W = winp[0];
  const int tid = threadIdx.x, w = tid >> 6, lane = tid & 63;
  const int l15 = lane & 15, l4 = lane >> 4;
  const size_t qkbase = (size_t)bh * NPAD * HD;
  const size_t vtb = (size_t)bh * HD * NPAD;
  const bool is_spec = (qt == 16);

  const int qrow0 = is_spec ? 0 : (4 + qt * 64 + w * 16);
  bf16x8 aq0 = *(const bf16x8*)&Q[qkbase + (size_t)(qrow0 + l15) * HD + l4 * 8];
  bf16x8 aq1 = *(const bf16x8*)&Q[qkbase + (size_t)(qrow0 + l15) * HD + 32 + l4 * 8];

  float mrow[4], lrow[4];
  f32x4 o[4] = {};
#pragma unroll
  for (int r = 0; r < 4; r++) { mrow[r] = -1e30f; lrow[r] = 0.0f; }

  int p0, pstep, pmax, toff;
  if (is_spec) {
    p0 = w; pstep = 4; pmax = 16; toff = -1;
  } else {
    int ta = ((2 * qt - W + 64) >> 1) - 32;
    int tb = (2 * qt + 1 + W) >> 1;
    ta = ta < 0 ? 0 : ta;
    tb = tb > 15 ? 15 : tb;
    p0 = 0; pstep = 1; pmax = tb - ta + 1; toff = ta - 1;
  }

  for (int p = p0; p <= pmax; p += pstep) {
    const bool sp = (p == 0);
    const int tau = toff + p;
    const int krow0 = sp ? 0 : (4 + tau * 64);
    const int vcol0 = sp ? 0 : (64 + tau * 64);

    f32x4 sacc[4] = {};
#pragma unroll
    for (int kf = 0; kf < 4; kf++) {
      const bf16* kp = &Kb[qkbase + (size_t)(krow0 + kf * 16 + l15) * HD];
      bf16x8 b0 = *(const bf16x8*)(kp + l4 * 8);
      bf16x8 b1 = *(const bf16x8*)(kp + 32 + l4 * 8);
      sacc[kf] = __builtin_amdgcn_mfma_f32_16x16x32_bf16(aq0, b0, sacc[kf], 0, 0, 0);
      sacc[kf] = __builtin_amdgcn_mfma_f32_16x16x32_bf16(aq1, b1, sacc[kf], 0, 0, 0);
    }

    float pvv[4][4];
#pragma unroll
    for (int kf = 0; kf < 4; kf++)
#pragma unroll
      for (int r = 0; r < 4; r++) {
        float s = sacc[kf][r] * 0.125f;
        bool valid;
        if (sp) {
          valid = (kf == 0) && (l15 < 4);
        } else if (is_spec) {
          valid = true;
        } else {
          int p_k = tau * 64 + kf * 16 + l15;
          int p_q = qt * 64 + w * 16 + l4 * 4 + r;
          int dr = (p_q >> 5) - (p_k >> 5); dr = dr < 0 ? -dr : dr;
          int dc = (p_q & 31) - (p_k & 31); dc = dc < 0 ? -dc : dc;
          valid = (dr <= W) && (dc <= W);
        }
        pvv[kf][r] = valid ? s : -1e30f;
      }

#pragma unroll
    for (int r = 0; r < 4; r++) {
      float mx = fmaxf(fmaxf(pvv[0][r], pvv[1][r]), fmaxf(pvv[2][r], pvv[3][r]));
#pragma unroll
      for (int mm = 1; mm < 16; mm <<= 1) mx = fmaxf(mx, __shfl_xor(mx, mm));
      float mnew = fmaxf(mrow[r], mx);
      float scale = __expf(mrow[r] - mnew);
      float rs = 0.0f;
#pragma unroll
      for (int kf = 0; kf < 4; kf++) {
        float pp = __expf(pvv[kf][r] - mnew);
        pvv[kf][r] = pp;
        rs += pp;
      }
#pragma unroll
      for (int mm = 1; mm < 16; mm <<= 1) rs += __shfl_xor(rs, mm);
      lrow[r] = lrow[r] * scale + rs;
      mrow[r] = mnew;
#pragma unroll
      for (int f = 0; f < 4; f++) o[f][r] *= scale;
    }

#pragma unroll
    for (int kf = 0; kf < 4; kf++)
#pragma unroll
      for (int r = 0; r < 4; r++)
        P_s[w][l4 * 4 + r][kf * 16 + l15] = (bf16)pvv[kf][r];

    bf16x8 pa0 = *(const bf16x8*)&P_s[w][l15][l4 * 8];
    bf16x8 pa1 = *(const bf16x8*)&P_s[w][l15][32 + l4 * 8];
#pragma unroll
    for (int f = 0; f < 4; f++) {
      const bf16* vp = &Vt[vtb + (size_t)(f * 16 + l15) * NPAD + vcol0];
      bf16x8 v0 = *(const bf16x8*)(vp + l4 * 8);
      bf16x8 v1 = *(const bf16x8*)(vp + 32 + l4 * 8);
      o[f] = __builtin_amdgcn_mfma_f32_16x16x32_bf16(pa0, v0, o[f], 0, 0, 0);
      o[f] = __builtin_amdgcn_mfma_f32_16x16x32_bf16(pa1, v1, o[f], 0, 0, 0);
    }
  }

  const int b = bh >> 4, h = bh & 15;
  if (!is_spec) {
#pragma unroll
    for (int f = 0; f < 4; f++)
#pragma unroll
      for (int r = 0; r < 4; r++) {
        int n = qrow0 + l4 * 4 + r;
        att[((size_t)(b * NSEQ + n)) * CDIM + h * HD + f * 16 + l15] =
            (bf16)(o[f][r] / lrow[r]);
      }
  } else {
    if (l4 == 0) {
#pragma unroll
      for (int f = 0; f < 4; f++)
#pragma unroll
        for (int r = 0; r < 4; r++) o_s[w][r][f * 16 + l15] = o[f][r];
      if (l15 == 0)
#pragma unroll
        for (int r = 0; r < 4; r++) { ml_s[w][0][r] = mrow[r]; ml_s[w][1][r] = lrow[r]; }
    }
    __syncthreads();
    int row = tid >> 6, dim = tid & 63;
    float M = -1e30f;
#pragma unroll
    for (int ww = 0; ww < 4; ww++) M = fmaxf(M, ml_s[ww][0][row]);
    float L = 0.0f, val = 0.0f;
#pragma unroll
    for (int ww = 0; ww < 4; ww++) {
      float e = __expf(ml_s[ww][0][row] - M);
      L += e * ml_s[ww][1][row];
      val += e * o_s[ww][row][dim];
    }
    att[((size_t)(b * NSEQ + row)) * CDIM + h * HD + dim] = (bf16)(val / L);
  }
}

// ------------------------------------------------------------------------
extern "C" void kernel_launch(void* const* d_in, const int* in_sizes, int n_in,
                              void* d_out, int out_size, void* d_ws, size_t ws_size,
                              hipStream_t stream) {
  const float* hidden = (const float*)d_in[0];
  const float* cosb = (const float*)d_in[1];
  const float* sinb = (const float*)d_in[2];
  const float* qkv_w = (const float*)d_in[3];
  const float* out_w = (const float*)d_in[4];
  const float* norm_q_w = (const float*)d_in[5];
  const float* norm_k_w = (const float*)d_in[6];
  const int* win = (const int*)d_in[7];
  float* out = (float*)d_out;

  char* ws = (char*)d_ws;
  size_t off = 0;
  auto alloc = [&](size_t bytes) {
    char* p = ws + off;
    off += (bytes + 255) & ~(size_t)255;
    return p;
  };
  bf16* A_bf  = (bf16*)alloc((size_t)M_REAL * CDIM * 2);
  bf16* W1    = (bf16*)alloc((size_t)3 * CDIM * CDIM * 2);
  bf16* W2    = (bf16*)alloc((size_t)CDIM * CDIM * 2);
  bf16* v_raw = (bf16*)alloc((size_t)BHN * NSEQ * HD * 2);
  bf16* q_bf  = (bf16*)alloc((size_t)BHN * NPAD * HD * 2);
  bf16* k_bf  = (bf16*)alloc((size_t)BHN * NPAD * HD * 2);
  bf16* vT    = (bf16*)alloc((size_t)BHN * HD * NPAD * 2);
  bf16* att   = (bf16*)alloc((size_t)M_REAL * CDIM * 2);
  (void)ws_size; (void)in_sizes; (void)n_in; (void)out_size;

  cast_pad_kernel<<<2048, 256, 0, stream>>>(hidden, A_bf, (long)M_REAL * CDIM, (long)M_REAL * CDIM);
  cast_pad_kernel<<<1024, 256, 0, stream>>>(qkv_w, W1, (long)3 * CDIM * CDIM, (long)3 * CDIM * CDIM);
  cast_pad_kernel<<<512, 256, 0, stream>>>(out_w, W2, (long)CDIM * CDIM, (long)CDIM * CDIM);

  // GEMM1: 8 XCD x 3 n-tiles x 33 m-tiles = 792 blocks; each XCD pins a
  // 384-col W1 strip (0.75MB) in its L2.
  gemm_bf16_kernel<0, 3><<<792, 256, 0, stream>>>(
      A_bf, W1, q_bf, k_bf, v_raw, nullptr, cosb, sinb, norm_q_w, norm_k_w);
  v_transpose_kernel<<<dim3(17, 64), 256, 0, stream>>>(v_raw, vT);
  attn_kernel<<<dim3(17, 64), 256, 0, stream>>>(q_bf, k_bf, vT, att, win);
  // GEMM2: 8 XCD x 1 n-tile x 33 m-tiles = 264 blocks; 0.25MB W2 strip/XCD.
  gemm_bf16_kernel<1, 1><<<264, 256, 0, stream>>>(
      att, W2, nullptr, nullptr, nullptr, out, nullptr, nullptr, nullptr, nullptr);
}

// Round 9
// 130.625 us; speedup vs baseline: 1.2132x; 1.0471x over previous
//
#include <hip/hip_runtime.h>
#include <hip/hip_bf16.h>
#include <stdint.h>

typedef __bf16 bf16;
typedef __attribute__((ext_vector_type(8))) __bf16 bf16x8;
typedef __attribute__((ext_vector_type(4))) __bf16 bf16x4;
typedef __attribute__((ext_vector_type(4))) float f32x4;

#define NSEQ 1028
#define CDIM 1024
#define NHEADS 16
#define HD 64
#define BHN 64          // B*H
#define NPAD 1088       // 17*64
#define M_REAL 4112     // B*NSEQ
#define MTILES 33       // 33 m-tiles of 128 (last starts at M_REAL-128, overlap)

static __device__ __forceinline__ void async_copy16(bf16* lds, const bf16* g) {
  __builtin_amdgcn_global_load_lds(
      (const __attribute__((address_space(1))) uint32_t*)g,
      (__attribute__((address_space(3))) uint32_t*)lds, 16, 0, 0);
}

// ---- fused fp32 -> bf16 cast for all three inputs (1 launch) ------------
__global__ __launch_bounds__(256) void cast3_kernel(
    const float* __restrict__ s0, bf16* __restrict__ d0, long n0,
    const float* __restrict__ s1, bf16* __restrict__ d1, long n1,
    const float* __restrict__ s2, bf16* __restrict__ d2, long n2) {
  long total = n0 + n1 + n2;   // all multiples of 4
  long t = (long)blockIdx.x * 256 + threadIdx.x;
  long stride = (long)gridDim.x * 256;
  for (long j = t * 4; j < total; j += stride * 4) {
    const float* s; bf16* d; long jj = j;
    if (jj < n0) { s = s0; d = d0; }
    else if (jj < n0 + n1) { s = s1; d = d1; jj -= n0; }
    else { s = s2; d = d2; jj -= n0 + n1; }
    float4 v = *(const float4*)(s + jj);
    bf16x4 o;
    o[0] = (bf16)v.x; o[1] = (bf16)v.y; o[2] = (bf16)v.z; o[3] = (bf16)v.w;
    *(bf16x4*)(d + jj) = o;
  }
}

// ---- bf16 MFMA GEMM, 128x128 tile, BK=32, dbuf, 4 blocks/CU (R9) ---------
// C[m][n] = sum_k A[m][k] * Bm[n][k], K = CDIM = 1024, 32 K-steps.
// LDS = 2 dbuf x (128x32) x {A,B} x 2B = 32 KiB -> 4 blocks/CU (VGPR-capped,
// __launch_bounds__(256,4)) = 2x the wave-level latency hiding of R4-R8
// (the one axis all five ~55us variants shared: 2 blocks/CU, occ 14.5%).
// LDS unit involution (rule #21, both sides): 16B unit u (9b: row<<2|chunk),
//   phys = u ^ ((u>>3)&7)  -- permutes chunk AND row-bit0; per-16-lane frag
// phase hits each 4-bank cluster exactly 2x (free), staging stays 64B-
// sector coalesced. Counted vmcnt(4), raw barriers, XCD weight-pinning map.
// EPI==0: fused RMS-norm+rope epilogue -> q_bf/k_bf [bh][NPAD][64] + v_raw.
// EPI==1: fp32 C row-major (N = NSTRIP*8*128 columns).
template <int EPI, int NSTRIP>
__global__ __launch_bounds__(256, 4) void gemm_bf16_kernel(
    const bf16* __restrict__ A, const bf16* __restrict__ Bm,
    bf16* __restrict__ q_bf, bf16* __restrict__ k_bf, bf16* __restrict__ v_raw,
    float* __restrict__ outF,
    const float* __restrict__ cosb, const float* __restrict__ sinb,
    const float* __restrict__ nqw, const float* __restrict__ nkw) {
  constexpr int K = CDIM;
  constexpr int N = NSTRIP * 8 * 128;
  __shared__ __attribute__((aligned(16))) bf16 As[2][128 * 32];
  __shared__ __attribute__((aligned(16))) bf16 Bs[2][128 * 32];
  const int tid = threadIdx.x;
  const int lane = tid & 63;
  const int wid = tid >> 6;
  const int wr = wid >> 1, wc = wid & 1;
  const int l15 = lane & 15, l4 = lane >> 4;

  // XCD weight-pinning work mapping (R8, kept: -2.2us, -14MB FETCH)
  const int xcd = blockIdx.x & 7;
  const int pos = blockIdx.x >> 3;          // 0 .. NSTRIP*MTILES-1
  const int nloc = pos % NSTRIP;
  const int mi = pos / NSTRIP;
  const int n0 = (xcd * NSTRIP + nloc) << 7;
  const int m0 = (mi < MTILES - 1) ? (mi << 7) : (M_REAL - 128);

  f32x4 acc[4][4] = {};

  // staging sources: thread slot c holds physical unit c -> fetch logical
  // unit u = c ^ ((c>>3)&7) (involution). row = u>>2, chunk = u&3 (16B).
  size_t a_base[2], b_base[2];
#pragma unroll
  for (int s = 0; s < 2; s++) {
    int c = tid + s * 256;
    int u = c ^ ((c >> 3) & 7);
    int row = u >> 2, ch = u & 3;
    a_base[s] = (size_t)(m0 + row) * K + (ch << 3);
    b_base[s] = (size_t)(n0 + row) * K + (ch << 3);
  }

#define STAGE(bufi, ktof)                                         \
  {                                                               \
    _Pragma("unroll")                                             \
    for (int s = 0; s < 2; s++) {                                 \
      int c = tid + s * 256;                                      \
      async_copy16(&As[bufi][c * 8], A + a_base[s] + (ktof));     \
      async_copy16(&Bs[bufi][c * 8], Bm + b_base[s] + (ktof));    \
    }                                                             \
  }

  const int nt = K >> 5;   // 32 K-steps
  STAGE(0, 0);             // 4 loads/thread in flight

  for (int t = 0; t < nt; ++t) {
    if (t + 1 < nt) {
      STAGE((t + 1) & 1, (t + 1) << 5);
      asm volatile("s_waitcnt vmcnt(4)" ::: "memory");   // tile t landed
    } else {
      asm volatile("s_waitcnt vmcnt(0)" ::: "memory");
    }
    __builtin_amdgcn_s_barrier();  // raw: tile t+1's loads stay in flight

    const int cur = t & 1;
    bf16x8 af[4], bfr[4];
#pragma unroll
    for (int i = 0; i < 4; i++) {
      int u = ((wr * 64 + i * 16 + l15) << 2) | l4;
      af[i] = *(const bf16x8*)&As[cur][(u ^ ((u >> 3) & 7)) << 3];
    }
#pragma unroll
    for (int j = 0; j < 4; j++) {
      int u = ((wc * 64 + j * 16 + l15) << 2) | l4;
      bfr[j] = *(const bf16x8*)&Bs[cur][(u ^ ((u >> 3) & 7)) << 3];
    }

#pragma unroll
    for (int i = 0; i < 4; i++)
#pragma unroll
      for (int j = 0; j < 4; j++)
        acc[i][j] = __builtin_amdgcn_mfma_f32_16x16x32_bf16(af[i], bfr[j], acc[i][j], 0, 0, 0);

    asm volatile("s_waitcnt lgkmcnt(0)" ::: "memory");   // buf[cur] reads done
    __builtin_amdgcn_s_barrier();
  }
#undef STAGE

  // epilogue: C/D layout col = lane&15, row = (lane>>4)*4 + reg
  if (EPI == 0) {
    const int d_base = n0 + wc * 64;      // 64-aligned -> one (matrix, head)
    const int tsel = d_base >> 10;
    const int hh = (d_base & 1023) >> 6;
    if (tsel == 2) {
#pragma unroll
      for (int i = 0; i < 4; i++)
#pragma unroll
        for (int r = 0; r < 4; r++) {
          int m = m0 + wr * 64 + i * 16 + l4 * 4 + r;   // always < M_REAL
          int b = m / NSEQ, n = m % NSEQ;
          size_t rb = ((size_t)(b * NHEADS + hh) * NSEQ + n) * HD;
#pragma unroll
          for (int j = 0; j < 4; j++)
            v_raw[rb + j * 16 + l15] = (bf16)acc[i][j][r];
        }
    } else {
      const float* wn = (tsel == 0) ? nqw : nkw;
      bf16* dst = (tsel == 0) ? q_bf : k_bf;
      float wv[4];
#pragma unroll
      for (int j = 0; j < 4; j++) wv[j] = wn[j * 16 + l15];
#pragma unroll
      for (int i = 0; i < 4; i++)
#pragma unroll
        for (int r = 0; r < 4; r++) {
          int m = m0 + wr * 64 + i * 16 + l4 * 4 + r;   // uniform across l15 group
          float ss = 0.0f;
#pragma unroll
          for (int j = 0; j < 4; j++) { float x = acc[i][j][r]; ss += x * x; }
          ss += __shfl_xor(ss, 1);
          ss += __shfl_xor(ss, 2);
          ss += __shfl_xor(ss, 4);
          ss += __shfl_xor(ss, 8);
          float rms = rsqrtf(ss * (1.0f / HD) + 1e-6f);
          int b = m / NSEQ, n = m % NSEQ;
          float qn[4];
#pragma unroll
          for (int j = 0; j < 4; j++) qn[j] = acc[i][j][r] * rms * wv[j];
          size_t rb = ((size_t)(b * NHEADS + hh) * NPAD + n) * HD;
#pragma unroll
          for (int j = 0; j < 4; j++) {
            float c = cosb[n * HD + j * 16 + l15];
            float s = sinb[n * HD + j * 16 + l15];
            float rot = (j < 2) ? -qn[j + 2] : qn[j - 2];
            dst[rb + j * 16 + l15] = (bf16)(qn[j] * c + rot * s);
          }
        }
    }
  } else {
#pragma unroll
    for (int i = 0; i < 4; i++)
#pragma unroll
      for (int j = 0; j < 4; j++) {
        int d = n0 + wc * 64 + j * 16 + l15;
        int mrow = m0 + wr * 64 + i * 16 + l4 * 4;
#pragma unroll
        for (int r = 0; r < 4; r++) {
          int m = mrow + r;   // always < M_REAL (overlap tile double-writes)
          outF[(size_t)m * N + d] = acc[i][j][r];
        }
      }
  }
}

// ---- V transpose: v_raw [bh][n][64] -> vT [bh][64][NPAD] patch-aligned ----
__global__ __launch_bounds__(256) void v_transpose_kernel(const bf16* __restrict__ v_raw,
                                                          bf16* __restrict__ vT) {
  __shared__ bf16 tile[64][65];
  int bh = blockIdx.y, c = blockIdx.x;
  int tid = threadIdx.x;
#pragma unroll
  for (int jj = 0; jj < 16; jj++) {
    int idx = tid + jj * 256;
    int i = idx >> 6, e = idx & 63;
    int n = (c == 0) ? i : (64 * c - 60 + i);
    bool ok = (c == 0) ? (i < 4) : (n < NSEQ);
    tile[i][e] = ok ? v_raw[((size_t)bh * NSEQ + n) * HD + e] : (bf16)0.0f;
  }
  __syncthreads();
#pragma unroll
  for (int jj = 0; jj < 16; jj++) {
    int idx = tid + jj * 256;
    int e = idx >> 6, i = idx & 63;
    vT[((size_t)bh * HD + e) * NPAD + 64 * c + i] = tile[i][e];
  }
}

// ---------------- masked flash attention (balanced tiling) ---------------
__global__ __launch_bounds__(256) void attn_kernel(
    const bf16* __restrict__ Q, const bf16* __restrict__ Kb, const bf16* __restrict__ Vt,
    bf16* __restrict__ att, const int* __restrict__ winp) {
  __shared__ __attribute__((aligned(16))) bf16 P_s[4][16][72];
  __shared__ float o_s[4][4][64];
  __shared__ float ml_s[4][2][16];
  const int bh = blockIdx.y, qt = blockIdx.x;
  const int W = winp[0];
  const int tid = threadIdx.x, w = tid >> 6, lane = tid & 63;
  const int l15 = lane & 15, l4 = lane >> 4;
  const size_t qkbase = (size_t)bh * NPAD * HD;
  const size_t vtb = (size_t)bh * HD * NPAD;
  const bool is_spec = (qt == 16);

  const int qrow0 = is_spec ? 0 : (4 + qt * 64 + w * 16);
  bf16x8 aq0 = *(const bf16x8*)&Q[qkbase + (size_t)(qrow0 + l15) * HD + l4 * 8];
  bf16x8 aq1 = *(const bf16x8*)&Q[qkbase + (size_t)(qrow0 + l15) * HD + 32 + l4 * 8];

  float mrow[4], lrow[4];
  f32x4 o[4] = {};
#pragma unroll
  for (int r = 0; r < 4; r++) { mrow[r] = -1e30f; lrow[r] = 0.0f; }

  int p0, pstep, pmax, toff;
  if (is_spec) {
    p0 = w; pstep = 4; pmax = 16; toff = -1;
  } else {
    int ta = ((2 * qt - W + 64) >> 1) - 32;
    int tb = (2 * qt + 1 + W) >> 1;
    ta = ta < 0 ? 0 : ta;
    tb = tb > 15 ? 15 : tb;
    p0 = 0; pstep = 1; pmax = tb - ta + 1; toff = ta - 1;
  }

  for (int p = p0; p <= pmax; p += pstep) {
    const bool sp = (p == 0);
    const int tau = toff + p;
    const int krow0 = sp ? 0 : (4 + tau * 64);
    const int vcol0 = sp ? 0 : (64 + tau * 64);

    f32x4 sacc[4] = {};
#pragma unroll
    for (int kf = 0; kf < 4; kf++) {
      const bf16* kp = &Kb[qkbase + (size_t)(krow0 + kf * 16 + l15) * HD];
      bf16x8 b0 = *(const bf16x8*)(kp + l4 * 8);
      bf16x8 b1 = *(const bf16x8*)(kp + 32 + l4 * 8);
      sacc[kf] = __builtin_amdgcn_mfma_f32_16x16x32_bf16(aq0, b0, sacc[kf], 0, 0, 0);
      sacc[kf] = __builtin_amdgcn_mfma_f32_16x16x32_bf16(aq1, b1, sacc[kf], 0, 0, 0);
    }

    float pvv[4][4];
#pragma unroll
    for (int kf = 0; kf < 4; kf++)
#pragma unroll
      for (int r = 0; r < 4; r++) {
        float s = sacc[kf][r] * 0.125f;
        bool valid;
        if (sp) {
          valid = (kf == 0) && (l15 < 4);
        } else if (is_spec) {
          valid = true;
        } else {
          int p_k = tau * 64 + kf * 16 + l15;
          int p_q = qt * 64 + w * 16 + l4 * 4 + r;
          int dr = (p_q >> 5) - (p_k >> 5); dr = dr < 0 ? -dr : dr;
          int dc = (p_q & 31) - (p_k & 31); dc = dc < 0 ? -dc : dc;
          valid = (dr <= W) && (dc <= W);
        }
        pvv[kf][r] = valid ? s : -1e30f;
      }

#pragma unroll
    for (int r = 0; r < 4; r++) {
      float mx = fmaxf(fmaxf(pvv[0][r], pvv[1][r]), fmaxf(pvv[2][r], pvv[3][r]));
#pragma unroll
      for (int mm = 1; mm < 16; mm <<= 1) mx = fmaxf(mx, __shfl_xor(mx, mm));
      float mnew = fmaxf(mrow[r], mx);
      float scale = __expf(mrow[r] - mnew);
      float rs = 0.0f;
#pragma unroll
      for (int kf = 0; kf < 4; kf++) {
        float pp = __expf(pvv[kf][r] - mnew);
        pvv[kf][r] = pp;
        rs += pp;
      }
#pragma unroll
      for (int mm = 1; mm < 16; mm <<= 1) rs += __shfl_xor(rs, mm);
      lrow[r] = lrow[r] * scale + rs;
      mrow[r] = mnew;
#pragma unroll
      for (int f = 0; f < 4; f++) o[f][r] *= scale;
    }

#pragma unroll
    for (int kf = 0; kf < 4; kf++)
#pragma unroll
      for (int r = 0; r < 4; r++)
        P_s[w][l4 * 4 + r][kf * 16 + l15] = (bf16)pvv[kf][r];

    bf16x8 pa0 = *(const bf16x8*)&P_s[w][l15][l4 * 8];
    bf16x8 pa1 = *(const bf16x8*)&P_s[w][l15][32 + l4 * 8];
#pragma unroll
    for (int f = 0; f < 4; f++) {
      const bf16* vp = &Vt[vtb + (size_t)(f * 16 + l15) * NPAD + vcol0];
      bf16x8 v0 = *(const bf16x8*)(vp + l4 * 8);
      bf16x8 v1 = *(const bf16x8*)(vp + 32 + l4 * 8);
      o[f] = __builtin_amdgcn_mfma_f32_16x16x32_bf16(pa0, v0, o[f], 0, 0, 0);
      o[f] = __builtin_amdgcn_mfma_f32_16x16x32_bf16(pa1, v1, o[f], 0, 0, 0);
    }
  }

  const int b = bh >> 4, h = bh & 15;
  if (!is_spec) {
#pragma unroll
    for (int f = 0; f < 4; f++)
#pragma unroll
      for (int r = 0; r < 4; r++) {
        int n = qrow0 + l4 * 4 + r;
        att[((size_t)(b * NSEQ + n)) * CDIM + h * HD + f * 16 + l15] =
            (bf16)(o[f][r] / lrow[r]);
      }
  } else {
    if (l4 == 0) {
#pragma unroll
      for (int f = 0; f < 4; f++)
#pragma unroll
        for (int r = 0; r < 4; r++) o_s[w][r][f * 16 + l15] = o[f][r];
      if (l15 == 0)
#pragma unroll
        for (int r = 0; r < 4; r++) { ml_s[w][0][r] = mrow[r]; ml_s[w][1][r] = lrow[r]; }
    }
    __syncthreads();
    int row = tid >> 6, dim = tid & 63;
    float M = -1e30f;
#pragma unroll
    for (int ww = 0; ww < 4; ww++) M = fmaxf(M, ml_s[ww][0][row]);
    float L = 0.0f, val = 0.0f;
#pragma unroll
    for (int ww = 0; ww < 4; ww++) {
      float e = __expf(ml_s[ww][0][row] - M);
      L += e * ml_s[ww][1][row];
      val += e * o_s[ww][row][dim];
    }
    att[((size_t)(b * NSEQ + row)) * CDIM + h * HD + dim] = (bf16)(val / L);
  }
}

// ------------------------------------------------------------------------
extern "C" void kernel_launch(void* const* d_in, const int* in_sizes, int n_in,
                              void* d_out, int out_size, void* d_ws, size_t ws_size,
                              hipStream_t stream) {
  const float* hidden = (const float*)d_in[0];
  const float* cosb = (const float*)d_in[1];
  const float* sinb = (const float*)d_in[2];
  const float* qkv_w = (const float*)d_in[3];
  const float* out_w = (const float*)d_in[4];
  const float* norm_q_w = (const float*)d_in[5];
  const float* norm_k_w = (const float*)d_in[6];
  const int* win = (const int*)d_in[7];
  float* out = (float*)d_out;

  char* ws = (char*)d_ws;
  size_t off = 0;
  auto alloc = [&](size_t bytes) {
    char* p = ws + off;
    off += (bytes + 255) & ~(size_t)255;
    return p;
  };
  bf16* A_bf  = (bf16*)alloc((size_t)M_REAL * CDIM * 2);
  bf16* W1    = (bf16*)alloc((size_t)3 * CDIM * CDIM * 2);
  bf16* W2    = (bf16*)alloc((size_t)CDIM * CDIM * 2);
  bf16* v_raw = (bf16*)alloc((size_t)BHN * NSEQ * HD * 2);
  bf16* q_bf  = (bf16*)alloc((size_t)BHN * NPAD * HD * 2);
  bf16* k_bf  = (bf16*)alloc((size_t)BHN * NPAD * HD * 2);
  bf16* vT    = (bf16*)alloc((size_t)BHN * HD * NPAD * 2);
  bf16* att   = (bf16*)alloc((size_t)M_REAL * CDIM * 2);
  (void)ws_size; (void)in_sizes; (void)n_in; (void)out_size;

  cast3_kernel<<<2048, 256, 0, stream>>>(
      hidden, A_bf, (long)M_REAL * CDIM,
      qkv_w, W1, (long)3 * CDIM * CDIM,
      out_w, W2, (long)CDIM * CDIM);

  // GEMM1: 8 XCD x 3 n-tiles x 33 m-tiles = 792 blocks; 0.75MB W1/XCD L2-pinned
  gemm_bf16_kernel<0, 3><<<792, 256, 0, stream>>>(
      A_bf, W1, q_bf, k_bf, v_raw, nullptr, cosb, sinb, norm_q_w, norm_k_w);
  v_transpose_kernel<<<dim3(17, 64), 256, 0, stream>>>(v_raw, vT);
  attn_kernel<<<dim3(17, 64), 256, 0, stream>>>(q_bf, k_bf, vT, att, win);
  // GEMM2: 8 XCD x 1 n-tile x 33 m-tiles = 264 blocks; 0.25MB W2/XCD L2-pinned
  gemm_bf16_kernel<1, 1><<<264, 256, 0, stream>>>(
      att, W2, nullptr, nullptr, nullptr, out, nullptr, nullptr, nullptr, nullptr);
}